// Round 18
// baseline (222.821 us; speedup 1.0000x reference)
//
#include <hip/hip_runtime.h>

// MAF forward, single-pass autoregressive. N=65536, D=32, H=1024, C=64.
// R17 = R16 with the TLP knob turned: 16 samples/wave (single tile), grid 512 x
//   512 thr -> 4096 waves = 16 waves/CU = 4/SIMD (R16: 2048 waves, 2/SIMD,
//   occupancy was GRID-limited at 22%). Keeps: cross-iteration W1/Wc register
//   ping-pong prefetch, ctx in registers, P in MFMA accumulators, W2 degree-
//   bucketed + q-permuted, barrier-free wave-private LDS.
// ws layout (bf16 u16):
//   [0      ..  32768)  W1mT [h=1024][d=32] = W1[d][h]*mask1 * 2log2e
//   [32768  ..  98304)  WcT  [h=1024][c=64] = Wc[c][h] * 2log2e
//   [98304  .. 225280)  W2g  [c=64][g=31][kw=64] degree-bucketed, q-permuted,
//                       zero-padded; ls cols * log2e
//   [225280 .. 227264)  b1g  [g=31][slot=64] bf16 = b1[h]*2log2e (0 pads)

#define NS 65536
#define K2LOG2E 2.885390082f
#define KLOG2E 1.4426950408889634f
#define KLN2 0.6931471805599453f

typedef __attribute__((ext_vector_type(8))) short short8;
typedef __attribute__((ext_vector_type(4))) float f32x4;

__device__ inline unsigned short f2bf(float f) {
  unsigned int u = __builtin_bit_cast(unsigned int, f);
  u += 0x7fffu + ((u >> 16) & 1u);          // RNE
  return (unsigned short)(u >> 16);
}
__device__ inline unsigned int cvt_pk_bf16(float lo, float hi) {
  unsigned int r;
  asm("v_cvt_pk_bf16_f32 %0, %1, %2" : "=v"(r) : "v"(lo), "v"(hi));
  return r;
}
__device__ inline float bf2f(unsigned short s) {
  return __builtin_bit_cast(float, (unsigned int)s << 16);
}
// input pre-scaled by 2log2e: tanh = 1 - 2/(1+exp2(z))
__device__ inline float tanh_pre(float z) {
  float t = __builtin_amdgcn_exp2f(z);
  float r = __builtin_amdgcn_rcpf(t + 1.0f);
  return fmaf(-2.0f, r, 1.0f);
}
__device__ inline short8 ld8bf(const float* p) {
  f32x4 a = *reinterpret_cast<const f32x4*>(p);
  f32x4 b = *reinterpret_cast<const f32x4*>(p + 4);
  union { short8 s; unsigned int u[4]; } t;
  t.u[0] = cvt_pk_bf16(a[0], a[1]);
  t.u[1] = cvt_pk_bf16(a[2], a[3]);
  t.u[2] = cvt_pk_bf16(b[0], b[1]);
  t.u[3] = cvt_pk_bf16(b[2], b[3]);
  return t.s;
}

__global__ void maf_prep(const float* __restrict__ W1, const float* __restrict__ Wc,
                         const float* __restrict__ W2, const float* __restrict__ b1,
                         unsigned short* __restrict__ ws) {
  int t = blockIdx.x * blockDim.x + threadIdx.x;
  if (t < 32768) {                                   // W1mT [h][d], masked+scaled
    int h = t >> 5, d = t & 31;
    int deg = h % 31 + 1;
    float v = (deg >= d + 1) ? W1[(size_t)d * 1024 + h] * K2LOG2E : 0.f;
    ws[t] = f2bf(v);
  } else if (t < 98304) {                            // WcT [h][c], scaled
    int i = t - 32768;
    int h = i >> 6, c = i & 63;
    ws[t] = f2bf(Wc[(size_t)c * 1024 + h] * K2LOG2E);
  } else if (t < 225280) {                           // W2g [c][g][kw]
    int i = t - 98304;
    int c = i / 1984, kpos = i % 1984;
    int g = kpos >> 6, kw = kpos & 63;
    int m = kw >> 5, rem = kw & 31;
    int lkk = rem >> 3, jp = (rem >> 2) & 1, r = rem & 3;
    int slot = (2 * m + jp) * 16 + 4 * lkk + r;      // q-perm -> slot within group
    int cnt = (g == 0) ? 34 : 33;
    float v = 0.f;
    if (slot < cnt) {
      int h = g + 31 * slot;                         // deg(h) == g+1
      int d = c >> 1;
      if (d > g) {                                   // mask2: out_deg > hid_deg
        v = W2[(size_t)h * 64 + c];
        if (c & 1) v *= KLOG2E;                      // ls cols in log2 domain
      }
    }
    ws[t] = f2bf(v);
  } else if (t < 227264) {                           // b1g [g][slot]
    int i = t - 225280;
    int g = i >> 6, slot = i & 63;
    int cnt = (g == 0) ? 34 : 33;
    float v = (slot < cnt) ? b1[g + 31 * slot] * K2LOG2E : 0.f;
    ws[t] = f2bf(v);
  }
}

__global__ __launch_bounds__(512, 4) void maf_main(
    const float* __restrict__ x, const float* __restrict__ ctx,
    const float* __restrict__ b2, const unsigned short* __restrict__ ws,
    float* __restrict__ out)
{
  // LDS: 10240 + 16896 = 27136 B -> 2 blocks/CU (grid 512). All wave-private.
  __shared__ __align__(16) unsigned short ybf[128][40];   // y bf16 [s][d]
  __shared__ __align__(16) float xT[32][132];             // x transposed [d][s]

  const unsigned short* W1mT = ws;             // [1024][32]
  const unsigned short* WcT  = ws + 32768;     // [1024][64]
  const unsigned short* W2g  = ws + 98304;     // [64][1984]
  const unsigned short* b1g  = ws + 225280;    // [1984]

  const int tid  = threadIdx.x;
  const int lane = tid & 63;
  const int w    = tid >> 6;        // wave 0..7: owns samples [16w, 16w+16)
  const int l15  = lane & 15;
  const int lk   = lane >> 4;
  const int s0   = blockIdx.x * 128;
  const int sw   = 16 * w;

  // ---- zero own ybf rows (16 rows x 40 u16 = 320 u32) ----
  {
    unsigned int* p = reinterpret_cast<unsigned int*>(&ybf[sw][0]);
    for (int i = lane; i < 320; i += 64) p[i] = 0u;
  }
  // ---- xT staging (wave-private: thread stages sample tid>>2) ----
  {
    int s = tid >> 2, q = tid & 3;
    const float* xp = x + (size_t)(s0 + s) * 32 + 8 * q;
    f32x4 v0 = *reinterpret_cast<const f32x4*>(xp);
    f32x4 v1 = *reinterpret_cast<const f32x4*>(xp + 4);
#pragma unroll
    for (int i = 0; i < 4; ++i) {
      xT[8 * q + i][s]     = v0[i];
      xT[8 * q + 4 + i][s] = v1[i];
    }
  }
  // ---- ctx -> registers (one-time) ----
  short8 cB0, cB1;
  {
    const float* c0 = ctx + (size_t)(s0 + sw + l15) * 64;
    cB0 = ld8bf(c0 + 8 * lk);
    cB1 = ld8bf(c0 + 32 + 8 * lk);
  }

  // ---- P accumulators (b2 folded; ls cols log2-scaled) ----
  f32x4 acc_0, acc_1, acc_2, acc_3;
  {
    float bs = (l15 & 1) ? KLOG2E : 1.0f;
    float v0 = b2[l15] * bs, v1 = b2[16 + l15] * bs;
    float v2 = b2[32 + l15] * bs, v3 = b2[48 + l15] * bs;
    acc_0 = (f32x4){v0, v0, v0, v0};
    acc_1 = (f32x4){v1, v1, v1, v1};
    acc_2 = (f32x4){v2, v2, v2, v2};
    acc_3 = (f32x4){v3, v3, v3, v3};
  }
  f32x4 ls0 = {0.f, 0.f, 0.f, 0.f};

#define LOADW(P, G) {                                                             \
    const int gg_ = (G);                                                          \
    const int cnt_ = (gg_ == 0) ? 34 : 33;                                        \
    _Pragma("unroll")                                                             \
    for (int ht = 0; ht < 3; ++ht) {                                              \
      int j_ = 16 * ht + l15;                                                     \
      bool vld_ = j_ < cnt_;                                                      \
      int h_ = vld_ ? (gg_ + 31 * j_) : 0;                                        \
      short8 a1_ = *reinterpret_cast<const short8*>(W1mT + (size_t)h_ * 32 + 8 * lk); \
      short8 a2_ = *reinterpret_cast<const short8*>(WcT + (size_t)h_ * 64 + 8 * lk);  \
      short8 a3_ = *reinterpret_cast<const short8*>(WcT + (size_t)h_ * 64 + 32 + 8 * lk); \
      short8 z_ = {0, 0, 0, 0, 0, 0, 0, 0};                                       \
      if (!vld_) { a1_ = z_; a2_ = z_; a3_ = z_; }                                \
      P##_w1[ht] = a1_; P##_c0[ht] = a2_; P##_c1[ht] = a3_;                       \
    } }

#define COMPUTE(P, G) {                                                           \
    const int gg_ = (G);                                                          \
    short8 w2b[4][2];                                                             \
    _Pragma("unroll")                                                             \
    for (int ct = 0; ct < 4; ++ct) {                                              \
      const unsigned short* wp_ = W2g + (size_t)(16 * ct + l15) * 1984 + 64 * gg_; \
      w2b[ct][0] = *reinterpret_cast<const short8*>(wp_ + 8 * lk);                \
      w2b[ct][1] = *reinterpret_cast<const short8*>(wp_ + 32 + 8 * lk);           \
    }                                                                             \
    short8 yB_ = *reinterpret_cast<const short8*>(&ybf[sw + l15][8 * lk]);        \
    unsigned int pa[3][2];                                                        \
    _Pragma("unroll")                                                             \
    for (int ht = 0; ht < 3; ++ht) {                                              \
      const unsigned short* bp_ = b1g + 64 * gg_ + 16 * ht + 4 * lk;              \
      f32x4 C = {bf2f(bp_[0]), bf2f(bp_[1]), bf2f(bp_[2]), bf2f(bp_[3])};         \
      C = __builtin_amdgcn_mfma_f32_16x16x32_bf16(P##_w1[ht], yB_, C, 0, 0, 0);   \
      C = __builtin_amdgcn_mfma_f32_16x16x32_bf16(P##_c0[ht], cB0, C, 0, 0, 0);   \
      C = __builtin_amdgcn_mfma_f32_16x16x32_bf16(P##_c1[ht], cB1, C, 0, 0, 0);   \
      pa[ht][0] = cvt_pk_bf16(tanh_pre(C[0]), tanh_pre(C[1]));                    \
      pa[ht][1] = cvt_pk_bf16(tanh_pre(C[2]), tanh_pre(C[3]));                    \
    }                                                                             \
    union { unsigned int u[4]; short8 s; } A0_, A1_;                              \
    A0_.u[0] = pa[0][0]; A0_.u[1] = pa[0][1];                                     \
    A0_.u[2] = pa[1][0]; A0_.u[3] = pa[1][1];                                     \
    A1_.u[0] = pa[2][0]; A1_.u[1] = pa[2][1]; A1_.u[2] = 0; A1_.u[3] = 0;         \
    PACC1(0) PACC1(1) PACC1(2) PACC1(3)                                           \
  }

#define PACC1(CT)                                                                 \
    acc_##CT = __builtin_amdgcn_mfma_f32_16x16x32_bf16(A0_.s, w2b[CT][0], acc_##CT, 0, 0, 0); \
    acc_##CT = __builtin_amdgcn_mfma_f32_16x16x32_bf16(A1_.s, w2b[CT][1], acc_##CT, 0, 0, 0);

#define EMIT(T) {                                                                 \
    const int t_ = (T);                                                           \
    const int cte_ = t_ >> 3;                                                     \
    const int li_ = 2 * (t_ & 7);                                                 \
    f32x4 av = cte_ == 0 ? acc_0 : cte_ == 1 ? acc_1 : cte_ == 2 ? acc_2 : acc_3; \
    f32x4 pv;                                                                     \
    _Pragma("unroll")                                                             \
    for (int r = 0; r < 4; ++r) pv[r] = __shfl_xor(av[r], 1);                     \
    if (l15 == li_) {                                                             \
      f32x4 x4 = *reinterpret_cast<const f32x4*>(&xT[t_][sw + 4 * lk]);           \
      _Pragma("unroll")                                                           \
      for (int r = 0; r < 4; ++r) {                                               \
        float y0 = fmaf(x4[r], __builtin_amdgcn_exp2f(pv[r]), av[r]);             \
        ybf[sw + 4 * lk + r][t_] = f2bf(y0);                                      \
        out[(size_t)(s0 + sw + 4 * lk + r) * 32 + t_] = y0;                       \
      }                                                                           \
      ls0 += pv;                                                                  \
    } }

  // ---- ping-pong weight sets ----
  short8 WA_w1[3], WA_c0[3], WA_c1[3];
  short8 WB_w1[3], WB_c0[3], WB_c1[3];
  LOADW(WA, 0)

#pragma unroll 1
  for (int t = 0; t < 30; t += 2) {
    EMIT(t)
    LOADW(WB, t + 1)
    COMPUTE(WA, t)
    EMIT(t + 1)
    LOADW(WA, t + 2)
    COMPUTE(WB, t + 1)
  }
  EMIT(30)
  COMPUTE(WA, 30)
  EMIT(31)

  // ---- log_det: sum over dims (lane bits 1..3 within the emit-lane group) ----
  {
    f32x4 v0 = ls0;
#pragma unroll
    for (int off = 2; off <= 8; off <<= 1)
#pragma unroll
      for (int r = 0; r < 4; ++r) v0[r] += __shfl_xor(v0[r], off);
    if (l15 == 0) {
#pragma unroll
      for (int r = 0; r < 4; ++r)
        out[(size_t)NS * 32 + s0 + sw + 4 * lk + r] = v0[r] * KLN2;
    }
  }
}

extern "C" void kernel_launch(void* const* d_in, const int* in_sizes, int n_in,
                              void* d_out, int out_size, void* d_ws, size_t ws_size,
                              hipStream_t stream) {
  (void)in_sizes; (void)n_in; (void)out_size; (void)ws_size;
  const float* x   = (const float*)d_in[0];
  const float* ctx = (const float*)d_in[1];
  const float* W1  = (const float*)d_in[2];
  const float* b1  = (const float*)d_in[3];
  const float* Wc  = (const float*)d_in[4];
  const float* W2  = (const float*)d_in[5];
  const float* b2  = (const float*)d_in[6];
  unsigned short* ws = (unsigned short*)d_ws;
  float* out = (float*)d_out;

  maf_prep<<<888, 256, 0, stream>>>(W1, Wc, W2, b1, ws);
  maf_main<<<512, 512, 0, stream>>>(x, ctx, b2, ws, out);
}

// Round 19
// 107.440 us; speedup vs baseline: 2.0739x; 2.0739x over previous
//
#include <hip/hip_runtime.h>

// MAF forward, single-pass autoregressive. N=65536, D=32, H=1024, C=64.
// R18: weight-gather amortization pushed to 64 samples/wave (4 sample-tiles).
//   Evidence R15/R16/R17: runtime scales with per-CU weight-gather count
//   (16 spw -> 220us twice at different occupancy; 32 spw -> 118us). TLP is
//   irrelevant (L1 gather path saturated); amortization is the lever.
//   - 4 waves x 256 thr x 256 blocks (1 blk/CU, 1 wave/SIMD, 512-reg cap)
//   - per step, ONE set of 17 weight gathers feeds 64 samples (2x R16)
//   - ALL weight loads ping-pong prefetched one step ahead (W1/Wc + W2 + b1)
//   - P in MFMA accumulators; W2 degree-bucketed + q-permuted; barrier-free.
// ws layout (bf16 u16):
//   [0      ..  32768)  W1mT [h=1024][d=32] = W1[d][h]*mask1 * 2log2e
//   [32768  ..  98304)  WcT  [h=1024][c=64] = Wc[c][h] * 2log2e
//   [98304  .. 225280)  W2g  [c=64][g=31][kw=64] degree-bucketed, q-permuted,
//                       zero-padded; ls cols * log2e
//   [225280 .. 227264)  b1g  [g=31][slot=64] bf16 = b1[h]*2log2e (0 pads)

#define NS 65536
#define K2LOG2E 2.885390082f
#define KLOG2E 1.4426950408889634f
#define KLN2 0.6931471805599453f

typedef __attribute__((ext_vector_type(8))) short short8;
typedef __attribute__((ext_vector_type(4))) float f32x4;

__device__ inline unsigned short f2bf(float f) {
  unsigned int u = __builtin_bit_cast(unsigned int, f);
  u += 0x7fffu + ((u >> 16) & 1u);          // RNE
  return (unsigned short)(u >> 16);
}
__device__ inline unsigned int cvt_pk_bf16(float lo, float hi) {
  unsigned int r;
  asm("v_cvt_pk_bf16_f32 %0, %1, %2" : "=v"(r) : "v"(lo), "v"(hi));
  return r;
}
__device__ inline float bf2f(unsigned short s) {
  return __builtin_bit_cast(float, (unsigned int)s << 16);
}
// input pre-scaled by 2log2e: tanh = 1 - 2/(1+exp2(z))
__device__ inline float tanh_pre(float z) {
  float t = __builtin_amdgcn_exp2f(z);
  float r = __builtin_amdgcn_rcpf(t + 1.0f);
  return fmaf(-2.0f, r, 1.0f);
}
__device__ inline short8 ld8bf(const float* p) {
  f32x4 a = *reinterpret_cast<const f32x4*>(p);
  f32x4 b = *reinterpret_cast<const f32x4*>(p + 4);
  union { short8 s; unsigned int u[4]; } t;
  t.u[0] = cvt_pk_bf16(a[0], a[1]);
  t.u[1] = cvt_pk_bf16(a[2], a[3]);
  t.u[2] = cvt_pk_bf16(b[0], b[1]);
  t.u[3] = cvt_pk_bf16(b[2], b[3]);
  return t.s;
}

__global__ void maf_prep(const float* __restrict__ W1, const float* __restrict__ Wc,
                         const float* __restrict__ W2, const float* __restrict__ b1,
                         unsigned short* __restrict__ ws) {
  int t = blockIdx.x * blockDim.x + threadIdx.x;
  if (t < 32768) {                                   // W1mT [h][d], masked+scaled
    int h = t >> 5, d = t & 31;
    int deg = h % 31 + 1;
    float v = (deg >= d + 1) ? W1[(size_t)d * 1024 + h] * K2LOG2E : 0.f;
    ws[t] = f2bf(v);
  } else if (t < 98304) {                            // WcT [h][c], scaled
    int i = t - 32768;
    int h = i >> 6, c = i & 63;
    ws[t] = f2bf(Wc[(size_t)c * 1024 + h] * K2LOG2E);
  } else if (t < 225280) {                           // W2g [c][g][kw]
    int i = t - 98304;
    int c = i / 1984, kpos = i % 1984;
    int g = kpos >> 6, kw = kpos & 63;
    int m = kw >> 5, rem = kw & 31;
    int lkk = rem >> 3, jp = (rem >> 2) & 1, r = rem & 3;
    int slot = (2 * m + jp) * 16 + 4 * lkk + r;      // q-perm -> slot within group
    int cnt = (g == 0) ? 34 : 33;
    float v = 0.f;
    if (slot < cnt) {
      int h = g + 31 * slot;                         // deg(h) == g+1
      int d = c >> 1;
      if (d > g) {                                   // mask2: out_deg > hid_deg
        v = W2[(size_t)h * 64 + c];
        if (c & 1) v *= KLOG2E;                      // ls cols in log2 domain
      }
    }
    ws[t] = f2bf(v);
  } else if (t < 227264) {                           // b1g [g][slot]
    int i = t - 225280;
    int g = i >> 6, slot = i & 63;
    int cnt = (g == 0) ? 34 : 33;
    float v = (slot < cnt) ? b1[g + 31 * slot] * K2LOG2E : 0.f;
    ws[t] = f2bf(v);
  }
}

__global__ __launch_bounds__(256, 1) void maf_main(
    const float* __restrict__ x, const float* __restrict__ ctx,
    const float* __restrict__ b2, const unsigned short* __restrict__ ws,
    float* __restrict__ out)
{
  // LDS: 20480 + 33280 = 53760 B. All wave-private; zero barriers.
  __shared__ __align__(16) unsigned short ybf[256][40];   // y bf16 [s][d]
  __shared__ __align__(16) float xT[32][260];             // x transposed [d][s]

  const unsigned short* W1mT = ws;             // [1024][32]
  const unsigned short* WcT  = ws + 32768;     // [1024][64]
  const unsigned short* W2g  = ws + 98304;     // [64][1984]
  const unsigned short* b1g  = ws + 225280;    // [1984]

  const int tid  = threadIdx.x;
  const int lane = tid & 63;
  const int w    = tid >> 6;        // wave 0..3: owns samples [64w, 64w+64)
  const int l15  = lane & 15;
  const int lk   = lane >> 4;
  const int s0   = blockIdx.x * 256;
  const int sw   = 64 * w;

  // ---- zero own ybf rows (64 rows x 40 u16 = 1280 u32) ----
  {
    unsigned int* p = reinterpret_cast<unsigned int*>(&ybf[sw][0]);
    for (int i = lane; i < 1280; i += 64) p[i] = 0u;
  }
  // ---- xT staging: thread stages its own sample (tid) -> wave-private cols ----
  {
    const float* xp = x + (size_t)(s0 + tid) * 32;
#pragma unroll
    for (int q = 0; q < 8; ++q) {
      f32x4 v = *reinterpret_cast<const f32x4*>(xp + 4 * q);
#pragma unroll
      for (int i = 0; i < 4; ++i) xT[4 * q + i][tid] = v[i];
    }
  }
  // ---- ctx -> registers (4 tiles x 2 frags) ----
  short8 cB[4][2];
#pragma unroll
  for (int st = 0; st < 4; ++st) {
    const float* c0 = ctx + (size_t)(s0 + sw + 16 * st + l15) * 64;
    cB[st][0] = ld8bf(c0 + 8 * lk);
    cB[st][1] = ld8bf(c0 + 32 + 8 * lk);
  }

  // ---- P accumulators acc[st][ct] (b2 folded; ls cols log2-scaled) ----
  f32x4 acc[4][4];
  {
    float bs = (l15 & 1) ? KLOG2E : 1.0f;
#pragma unroll
    for (int ct = 0; ct < 4; ++ct) {
      float v = b2[16 * ct + l15] * bs;
      f32x4 bv = {v, v, v, v};
#pragma unroll
      for (int st = 0; st < 4; ++st) acc[st][ct] = bv;
    }
  }
  f32x4 ls[4];
#pragma unroll
  for (int st = 0; st < 4; ++st) ls[st] = (f32x4){0.f, 0.f, 0.f, 0.f};

#define LOADW(P, G) {                                                             \
    const int gg_ = (G);                                                          \
    const int cnt_ = (gg_ == 0) ? 34 : 33;                                        \
    _Pragma("unroll")                                                             \
    for (int ht = 0; ht < 3; ++ht) {                                              \
      int j_ = 16 * ht + l15;                                                     \
      bool vld_ = j_ < cnt_;                                                      \
      int h_ = vld_ ? (gg_ + 31 * j_) : 0;                                        \
      short8 a1_ = *reinterpret_cast<const short8*>(W1mT + (size_t)h_ * 32 + 8 * lk); \
      short8 a2_ = *reinterpret_cast<const short8*>(WcT + (size_t)h_ * 64 + 8 * lk);  \
      short8 a3_ = *reinterpret_cast<const short8*>(WcT + (size_t)h_ * 64 + 32 + 8 * lk); \
      short8 z_ = {0, 0, 0, 0, 0, 0, 0, 0};                                       \
      if (!vld_) { a1_ = z_; a2_ = z_; a3_ = z_; }                                \
      P##_w1[ht] = a1_; P##_c0[ht] = a2_; P##_c1[ht] = a3_;                       \
    } }

#define LOADW2(P, G) {                                                            \
    const int gg_ = (G);                                                          \
    _Pragma("unroll")                                                             \
    for (int ct = 0; ct < 4; ++ct) {                                              \
      const unsigned short* wp_ = W2g + (size_t)(16 * ct + l15) * 1984 + 64 * gg_; \
      P##_w2[ct][0] = *reinterpret_cast<const short8*>(wp_ + 8 * lk);             \
      P##_w2[ct][1] = *reinterpret_cast<const short8*>(wp_ + 32 + 8 * lk);        \
    } }

#define LOADB(P, G) {                                                             \
    const int gg_ = (G);                                                          \
    _Pragma("unroll")                                                             \
    for (int ht = 0; ht < 3; ++ht) {                                              \
      const unsigned short* bp_ = b1g + 64 * gg_ + 16 * ht + 4 * lk;              \
      P##_b1[ht] = (f32x4){bf2f(bp_[0]), bf2f(bp_[1]), bf2f(bp_[2]), bf2f(bp_[3])}; \
    } }

#define COMPUTE(P, G) {                                                           \
    _Pragma("unroll")                                                             \
    for (int st = 0; st < 4; ++st) {                                              \
      short8 yB_ = *reinterpret_cast<const short8*>(&ybf[sw + 16 * st + l15][8 * lk]); \
      unsigned int pa[3][2];                                                      \
      _Pragma("unroll")                                                           \
      for (int ht = 0; ht < 3; ++ht) {                                            \
        f32x4 C = P##_b1[ht];                                                     \
        C = __builtin_amdgcn_mfma_f32_16x16x32_bf16(P##_w1[ht], yB_, C, 0, 0, 0); \
        C = __builtin_amdgcn_mfma_f32_16x16x32_bf16(P##_c0[ht], cB[st][0], C, 0, 0, 0); \
        C = __builtin_amdgcn_mfma_f32_16x16x32_bf16(P##_c1[ht], cB[st][1], C, 0, 0, 0); \
        pa[ht][0] = cvt_pk_bf16(tanh_pre(C[0]), tanh_pre(C[1]));                  \
        pa[ht][1] = cvt_pk_bf16(tanh_pre(C[2]), tanh_pre(C[3]));                  \
      }                                                                           \
      union { unsigned int u[4]; short8 s; } A0_, A1_;                            \
      A0_.u[0] = pa[0][0]; A0_.u[1] = pa[0][1];                                   \
      A0_.u[2] = pa[1][0]; A0_.u[3] = pa[1][1];                                   \
      A1_.u[0] = pa[2][0]; A1_.u[1] = pa[2][1]; A1_.u[2] = 0; A1_.u[3] = 0;       \
      _Pragma("unroll")                                                           \
      for (int ct = 0; ct < 4; ++ct) {                                            \
        acc[st][ct] = __builtin_amdgcn_mfma_f32_16x16x32_bf16(A0_.s, P##_w2[ct][0], acc[st][ct], 0, 0, 0); \
        acc[st][ct] = __builtin_amdgcn_mfma_f32_16x16x32_bf16(A1_.s, P##_w2[ct][1], acc[st][ct], 0, 0, 0); \
      }                                                                           \
    } }

#define EMIT(T) {                                                                 \
    const int t_ = (T);                                                           \
    const int cte_ = t_ >> 3;                                                     \
    const int li_ = 2 * (t_ & 7);                                                 \
    _Pragma("unroll")                                                             \
    for (int st = 0; st < 4; ++st) {                                              \
      f32x4 av = cte_ == 0 ? acc[st][0] : cte_ == 1 ? acc[st][1]                  \
               : cte_ == 2 ? acc[st][2] : acc[st][3];                             \
      f32x4 pv;                                                                   \
      _Pragma("unroll")                                                           \
      for (int r = 0; r < 4; ++r) pv[r] = __shfl_xor(av[r], 1);                   \
      if (l15 == li_) {                                                           \
        f32x4 x4 = *reinterpret_cast<const f32x4*>(&xT[t_][sw + 16 * st + 4 * lk]); \
        _Pragma("unroll")                                                         \
        for (int r = 0; r < 4; ++r) {                                             \
          float y0 = fmaf(x4[r], __builtin_amdgcn_exp2f(pv[r]), av[r]);           \
          ybf[sw + 16 * st + 4 * lk + r][t_] = f2bf(y0);                          \
          out[(size_t)(s0 + sw + 16 * st + 4 * lk + r) * 32 + t_] = y0;           \
        }                                                                         \
        ls[st] += pv;                                                             \
      }                                                                           \
    } }

  // ---- ping-pong weight sets ----
  short8 WA_w1[3], WA_c0[3], WA_c1[3], WA_w2[4][2];
  short8 WB_w1[3], WB_c0[3], WB_c1[3], WB_w2[4][2];
  f32x4 WA_b1[3], WB_b1[3];
  LOADW(WA, 0) LOADW2(WA, 0) LOADB(WA, 0)

#pragma unroll 1
  for (int t = 0; t < 30; t += 2) {
    EMIT(t)
    LOADW(WB, t + 1) LOADW2(WB, t + 1) LOADB(WB, t + 1)
    COMPUTE(WA, t)
    EMIT(t + 1)
    LOADW(WA, t + 2) LOADW2(WA, t + 2) LOADB(WA, t + 2)
    COMPUTE(WB, t + 1)
  }
  EMIT(30)
  COMPUTE(WA, 30)
  EMIT(31)

  // ---- log_det: reduce over even-l15 lanes (bits 1..3), per tile ----
#pragma unroll
  for (int st = 0; st < 4; ++st) {
    f32x4 v = ls[st];
#pragma unroll
    for (int off = 2; off <= 8; off <<= 1)
#pragma unroll
      for (int r = 0; r < 4; ++r) v[r] += __shfl_xor(v[r], off);
    if (l15 == 0) {
#pragma unroll
      for (int r = 0; r < 4; ++r)
        out[(size_t)NS * 32 + s0 + sw + 16 * st + 4 * lk + r] = v[r] * KLN2;
    }
  }
}

extern "C" void kernel_launch(void* const* d_in, const int* in_sizes, int n_in,
                              void* d_out, int out_size, void* d_ws, size_t ws_size,
                              hipStream_t stream) {
  (void)in_sizes; (void)n_in; (void)out_size; (void)ws_size;
  const float* x   = (const float*)d_in[0];
  const float* ctx = (const float*)d_in[1];
  const float* W1  = (const float*)d_in[2];
  const float* b1  = (const float*)d_in[3];
  const float* Wc  = (const float*)d_in[4];
  const float* W2  = (const float*)d_in[5];
  const float* b2  = (const float*)d_in[6];
  unsigned short* ws = (unsigned short*)d_ws;
  float* out = (float*)d_out;

  maf_prep<<<888, 256, 0, stream>>>(W1, Wc, W2, b1, ws);
  maf_main<<<256, 256, 0, stream>>>(x, ctx, b2, ws, out);
}

// Round 22
// 93.906 us; speedup vs baseline: 2.3728x; 1.1441x over previous
//
#include <hip/hip_runtime.h>

// MAF forward, single-pass autoregressive. N=65536, D=32, H=1024, C=64.
// R21 = BISECTION of R19/R20's NaN. Base is R18 (last PASS, 107us) verbatim;
//   ONLY the W2 path is pre-swizzled (W2f coalesced chunk0 frags + W2t 256B
//   tail for the 2 live chunk1 slots). W1/Wc/b1 keep R18's proven layouts and
//   demand-gather loads. PASS -> R19's bug is in the W1f/Wcf prep; NaN -> bug
//   is in W2f/W2t. All offsets recomputed fresh for this layout.
// ws layout (u16):
//   [0      ..  32768)  W1mT [h=1024][d=32] = W1[d][h]*mask1 * 2log2e   (R18)
//   [32768  ..  98304)  WcT  [h=1024][c=64] = Wc[c][h] * 2log2e          (R18)
//   [98304  .. 161792)  W2f  [g=31][ct=4][lane=64][e=8] chunk0 B-frags (q-perm)
//   [161792 .. 165760)  W2t  [g=31][c=64][which=2] slots 32/33 tail
//   [165760 .. 167744)  b1g  [g=31][slot=64] = b1*2log2e (0 pads)        (R18)

#define NS 65536
#define K2LOG2E 2.885390082f
#define KLOG2E 1.4426950408889634f
#define KLN2 0.6931471805599453f

typedef __attribute__((ext_vector_type(8))) short short8;
typedef __attribute__((ext_vector_type(4))) float f32x4;

__device__ inline unsigned short f2bf(float f) {
  unsigned int u = __builtin_bit_cast(unsigned int, f);
  u += 0x7fffu + ((u >> 16) & 1u);          // RNE
  return (unsigned short)(u >> 16);
}
__device__ inline unsigned int cvt_pk_bf16(float lo, float hi) {
  unsigned int r;
  asm("v_cvt_pk_bf16_f32 %0, %1, %2" : "=v"(r) : "v"(lo), "v"(hi));
  return r;
}
__device__ inline float bf2f(unsigned short s) {
  return __builtin_bit_cast(float, (unsigned int)s << 16);
}
// input pre-scaled by 2log2e: tanh = 1 - 2/(1+exp2(z))
__device__ inline float tanh_pre(float z) {
  float t = __builtin_amdgcn_exp2f(z);
  float r = __builtin_amdgcn_rcpf(t + 1.0f);
  return fmaf(-2.0f, r, 1.0f);
}
__device__ inline short8 ld8bf(const float* p) {
  f32x4 a = *reinterpret_cast<const f32x4*>(p);
  f32x4 b = *reinterpret_cast<const f32x4*>(p + 4);
  union { short8 s; unsigned int u[4]; } t;
  t.u[0] = cvt_pk_bf16(a[0], a[1]);
  t.u[1] = cvt_pk_bf16(a[2], a[3]);
  t.u[2] = cvt_pk_bf16(b[0], b[1]);
  t.u[3] = cvt_pk_bf16(b[2], b[3]);
  return t.s;
}

__global__ void maf_prep(const float* __restrict__ W1, const float* __restrict__ Wc,
                         const float* __restrict__ W2, const float* __restrict__ b1,
                         unsigned short* __restrict__ ws) {
  int t = blockIdx.x * blockDim.x + threadIdx.x;
  if (t < 32768) {                                   // W1mT [h][d], masked+scaled
    int h = t >> 5, d = t & 31;
    int deg = h % 31 + 1;
    float v = (deg >= d + 1) ? W1[(size_t)d * 1024 + h] * K2LOG2E : 0.f;
    ws[t] = f2bf(v);
  } else if (t < 98304) {                            // WcT [h][c], scaled
    int i = t - 32768;
    int h = i >> 6, c = i & 63;
    ws[t] = f2bf(Wc[(size_t)c * 1024 + h] * K2LOG2E);
  } else if (t < 161792) {                           // W2f: chunk0 B-frags (q-perm)
    int i = t - 98304;
    int g = i / 2048, r = i % 2048;
    int ct = r >> 9, q = r & 511;
    int lane = q >> 3, e = q & 7;
    int l15 = lane & 15, lk = lane >> 4;
    int c = 16 * ct + l15;
    int kw = 8 * lk + e;                             // 0..31 (chunk0)
    int lkk = kw >> 3, jp = (kw >> 2) & 1, rr = kw & 3;
    int slot = jp * 16 + 4 * lkk + rr;               // q-perm slot (<32)
    int cnt = (g == 0) ? 34 : 33;
    int h = g + 31 * slot, d = c >> 1;
    float v = (slot < cnt && d > g) ? W2[(size_t)h * 64 + c] : 0.f;
    if (c & 1) v *= KLOG2E;
    ws[t] = f2bf(v);
  } else if (t < 165760) {                           // W2t: slots 32/33 tail
    int i = t - 161792;
    int g = i >> 7, r = i & 127;
    int c = r >> 1, which = r & 1;
    int slot = 32 + which;
    int cnt = (g == 0) ? 34 : 33;
    int h = g + 31 * slot, d = c >> 1;
    float v = (slot < cnt && d > g) ? W2[(size_t)h * 64 + c] : 0.f;
    if (c & 1) v *= KLOG2E;
    ws[t] = f2bf(v);
  } else if (t < 167744) {                           // b1g [g][slot]
    int i = t - 165760;
    int g = i >> 6, sl = i & 63;
    int cnt = (g == 0) ? 34 : 33;
    float v = (sl < cnt) ? b1[g + 31 * sl] * K2LOG2E : 0.f;
    ws[t] = f2bf(v);
  }
}

__global__ __launch_bounds__(256, 1) void maf_main(
    const float* __restrict__ x, const float* __restrict__ ctx,
    const float* __restrict__ b2, const unsigned short* __restrict__ ws,
    float* __restrict__ out)
{
  // LDS: 20480 + 33280 = 53760 B. All wave-private; zero barriers.
  __shared__ __align__(16) unsigned short ybf[256][40];   // y bf16 [s][d]
  __shared__ __align__(16) float xT[32][260];             // x transposed [d][s]

  const unsigned short* W1mT = ws;             // [1024][32]
  const unsigned short* WcT  = ws + 32768;     // [1024][64]
  const unsigned short* W2f  = ws + 98304;     // [31][4][512]
  const unsigned short* W2t  = ws + 161792;    // [31][128]
  const unsigned short* b1g  = ws + 165760;    // [31][64]

  const int tid  = threadIdx.x;
  const int lane = tid & 63;
  const int w    = tid >> 6;        // wave 0..3: owns samples [64w, 64w+64)
  const int l15  = lane & 15;
  const int lk   = lane >> 4;
  const int s0   = blockIdx.x * 256;
  const int sw   = 64 * w;

  // ---- zero own ybf rows (64 rows x 40 u16 = 1280 u32) ----
  {
    unsigned int* p = reinterpret_cast<unsigned int*>(&ybf[sw][0]);
    for (int i = lane; i < 1280; i += 64) p[i] = 0u;
  }
  // ---- xT staging: thread stages its own sample (tid) -> wave-private cols ----
  {
    const float* xp = x + (size_t)(s0 + tid) * 32;
#pragma unroll
    for (int q = 0; q < 8; ++q) {
      f32x4 v = *reinterpret_cast<const f32x4*>(xp + 4 * q);
#pragma unroll
      for (int i = 0; i < 4; ++i) xT[4 * q + i][tid] = v[i];
    }
  }
  // ---- ctx -> registers (4 tiles x 2 frags) ----
  short8 cB[4][2];
#pragma unroll
  for (int st = 0; st < 4; ++st) {
    const float* c0 = ctx + (size_t)(s0 + sw + 16 * st + l15) * 64;
    cB[st][0] = ld8bf(c0 + 8 * lk);
    cB[st][1] = ld8bf(c0 + 32 + 8 * lk);
  }

  // ---- P accumulators acc[st][ct] (b2 folded; ls cols log2-scaled) ----
  f32x4 acc[4][4];
  {
    float bs = (l15 & 1) ? KLOG2E : 1.0f;
#pragma unroll
    for (int ct = 0; ct < 4; ++ct) {
      float v = b2[16 * ct + l15] * bs;
      f32x4 bv = {v, v, v, v};
#pragma unroll
      for (int st = 0; st < 4; ++st) acc[st][ct] = bv;
    }
  }
  f32x4 ls[4];
#pragma unroll
  for (int st = 0; st < 4; ++st) ls[st] = (f32x4){0.f, 0.f, 0.f, 0.f};

#define LOADW(P, G) {                                                             \
    const int gg_ = (G);                                                          \
    const int cnt_ = (gg_ == 0) ? 34 : 33;                                        \
    _Pragma("unroll")                                                             \
    for (int ht = 0; ht < 3; ++ht) {                                              \
      int j_ = 16 * ht + l15;                                                     \
      bool vld_ = j_ < cnt_;                                                      \
      int h_ = vld_ ? (gg_ + 31 * j_) : 0;                                        \
      short8 a1_ = *reinterpret_cast<const short8*>(W1mT + (size_t)h_ * 32 + 8 * lk); \
      short8 a2_ = *reinterpret_cast<const short8*>(WcT + (size_t)h_ * 64 + 8 * lk);  \
      short8 a3_ = *reinterpret_cast<const short8*>(WcT + (size_t)h_ * 64 + 32 + 8 * lk); \
      short8 z_ = {0, 0, 0, 0, 0, 0, 0, 0};                                       \
      if (!vld_) { a1_ = z_; a2_ = z_; a3_ = z_; }                                \
      P##_w1[ht] = a1_; P##_c0[ht] = a2_; P##_c1[ht] = a3_;                       \
    } }

#define LOADW2(P, G) {                                                            \
    const int gg_ = (G);                                                          \
    _Pragma("unroll")                                                             \
    for (int ct = 0; ct < 4; ++ct) {                                              \
      P##_w2[ct] = *reinterpret_cast<const short8*>(W2f + (size_t)(gg_ * 4 + ct) * 512 + lane * 8); \
      unsigned int tv = *reinterpret_cast<const unsigned int*>(W2t + (size_t)gg_ * 128 + 2 * (16 * ct + l15)); \
      P##_t2[ct] = (lk == 0) ? tv : 0u;                                           \
    } }

#define LOADB(P, G) {                                                             \
    const int gg_ = (G);                                                          \
    _Pragma("unroll")                                                             \
    for (int ht = 0; ht < 3; ++ht) {                                              \
      const unsigned short* bp_ = b1g + 64 * gg_ + 16 * ht + 4 * lk;              \
      P##_b1[ht] = (f32x4){bf2f(bp_[0]), bf2f(bp_[1]), bf2f(bp_[2]), bf2f(bp_[3])}; \
    } }

#define COMPUTE(P, G) {                                                           \
    _Pragma("unroll")                                                             \
    for (int st = 0; st < 4; ++st) {                                              \
      short8 yB_ = *reinterpret_cast<const short8*>(&ybf[sw + 16 * st + l15][8 * lk]); \
      unsigned int pa[3][2];                                                      \
      _Pragma("unroll")                                                           \
      for (int ht = 0; ht < 3; ++ht) {                                            \
        f32x4 C = P##_b1[ht];                                                     \
        C = __builtin_amdgcn_mfma_f32_16x16x32_bf16(P##_w1[ht], yB_, C, 0, 0, 0); \
        C = __builtin_amdgcn_mfma_f32_16x16x32_bf16(P##_c0[ht], cB[st][0], C, 0, 0, 0); \
        C = __builtin_amdgcn_mfma_f32_16x16x32_bf16(P##_c1[ht], cB[st][1], C, 0, 0, 0); \
        pa[ht][0] = cvt_pk_bf16(tanh_pre(C[0]), tanh_pre(C[1]));                  \
        pa[ht][1] = cvt_pk_bf16(tanh_pre(C[2]), tanh_pre(C[3]));                  \
      }                                                                           \
      union { unsigned int u[4]; short8 s; } A0_, A1_, B1_;                       \
      A0_.u[0] = pa[0][0]; A0_.u[1] = pa[0][1];                                   \
      A0_.u[2] = pa[1][0]; A0_.u[3] = pa[1][1];                                   \
      A1_.u[0] = pa[2][0]; A1_.u[1] = pa[2][1]; A1_.u[2] = 0; A1_.u[3] = 0;       \
      _Pragma("unroll")                                                           \
      for (int ct = 0; ct < 4; ++ct) {                                            \
        B1_.u[0] = P##_t2[ct]; B1_.u[1] = 0; B1_.u[2] = 0; B1_.u[3] = 0;          \
        acc[st][ct] = __builtin_amdgcn_mfma_f32_16x16x32_bf16(A0_.s, P##_w2[ct], acc[st][ct], 0, 0, 0); \
        acc[st][ct] = __builtin_amdgcn_mfma_f32_16x16x32_bf16(A1_.s, B1_.s, acc[st][ct], 0, 0, 0); \
      }                                                                           \
    } }

#define EMIT(T) {                                                                 \
    const int t_ = (T);                                                           \
    const int cte_ = t_ >> 3;                                                     \
    const int li_ = 2 * (t_ & 7);                                                 \
    _Pragma("unroll")                                                             \
    for (int st = 0; st < 4; ++st) {                                              \
      f32x4 av = cte_ == 0 ? acc[st][0] : cte_ == 1 ? acc[st][1]                  \
               : cte_ == 2 ? acc[st][2] : acc[st][3];                             \
      f32x4 pv;                                                                   \
      _Pragma("unroll")                                                           \
      for (int r = 0; r < 4; ++r) pv[r] = __shfl_xor(av[r], 1);                   \
      if (l15 == li_) {                                                           \
        f32x4 x4 = *reinterpret_cast<const f32x4*>(&xT[t_][sw + 16 * st + 4 * lk]); \
        _Pragma("unroll")                                                         \
        for (int r = 0; r < 4; ++r) {                                             \
          float y0 = fmaf(x4[r], __builtin_amdgcn_exp2f(pv[r]), av[r]);           \
          ybf[sw + 16 * st + 4 * lk + r][t_] = f2bf(y0);                          \
          out[(size_t)(s0 + sw + 16 * st + 4 * lk + r) * 32 + t_] = y0;           \
        }                                                                         \
        ls[st] += pv;                                                             \
      }                                                                           \
    } }

  // ---- ping-pong weight sets ----
  short8 WA_w1[3], WA_c0[3], WA_c1[3], WA_w2[4];
  short8 WB_w1[3], WB_c0[3], WB_c1[3], WB_w2[4];
  unsigned int WA_t2[4], WB_t2[4];
  f32x4 WA_b1[3], WB_b1[3];
  LOADW(WA, 0) LOADW2(WA, 0) LOADB(WA, 0)

#pragma unroll 1
  for (int t = 0; t < 30; t += 2) {
    EMIT(t)
    LOADW(WB, t + 1) LOADW2(WB, t + 1) LOADB(WB, t + 1)
    COMPUTE(WA, t)
    EMIT(t + 1)
    LOADW(WA, t + 2) LOADW2(WA, t + 2) LOADB(WA, t + 2)
    COMPUTE(WB, t + 1)
  }
  EMIT(30)
  COMPUTE(WA, 30)
  EMIT(31)

  // ---- log_det: reduce over even-l15 lanes (bits 1..3), per tile ----
#pragma unroll
  for (int st = 0; st < 4; ++st) {
    f32x4 v = ls[st];
#pragma unroll
    for (int off = 2; off <= 8; off <<= 1)
#pragma unroll
      for (int r = 0; r < 4; ++r) v[r] += __shfl_xor(v[r], off);
    if (l15 == 0) {
#pragma unroll
      for (int r = 0; r < 4; ++r)
        out[(size_t)NS * 32 + s0 + sw + 16 * st + 4 * lk + r] = v[r] * KLN2;
    }
  }
}

extern "C" void kernel_launch(void* const* d_in, const int* in_sizes, int n_in,
                              void* d_out, int out_size, void* d_ws, size_t ws_size,
                              hipStream_t stream) {
  (void)in_sizes; (void)n_in; (void)out_size; (void)ws_size;
  const float* x   = (const float*)d_in[0];
  const float* ctx = (const float*)d_in[1];
  const float* W1  = (const float*)d_in[2];
  const float* b1  = (const float*)d_in[3];
  const float* Wc  = (const float*)d_in[4];
  const float* W2  = (const float*)d_in[5];
  const float* b2  = (const float*)d_in[6];
  unsigned short* ws = (unsigned short*)d_ws;
  float* out = (float*)d_out;

  maf_prep<<<656, 256, 0, stream>>>(W1, Wc, W2, b1, ws);
  maf_main<<<256, 256, 0, stream>>>(x, ctx, b2, ws, out);
}

// Round 23
// 93.773 us; speedup vs baseline: 2.3762x; 1.0014x over previous
//
#include <hip/hip_runtime.h>

// MAF forward, single-pass autoregressive. N=65536, D=32, H=1024, C=64.
// R22 = R21 (PASS, 94us: W2 pre-swizzled, W1/Wc/b1 demand-gather) + bisection
//   step 2: W1f coalesced A-frags APPENDED at the end of R21's proven layout
//   (no working region relocated). LOADW's w1 gather -> one 1KB stream; c0/c1
//   keep R18's proven gathers. PASS -> R19's bug X was in Wcf; NaN -> X = W1f.
// ws layout (u16):
//   [0      ..  32768)  W1mT [h=1024][d=32] = W1[d][h]*mask1 * 2log2e   (R18)
//   [32768  ..  98304)  WcT  [h=1024][c=64] = Wc[c][h] * 2log2e          (R18)
//   [98304  .. 161792)  W2f  [g=31][ct=4][lane=64][e=8] chunk0 B-frags (q-perm)
//   [161792 .. 165760)  W2t  [g=31][c=64][which=2] slots 32/33 tail
//   [165760 .. 167744)  b1g  [g=31][slot=64] = b1*2log2e (0 pads)        (R18)
//   [167744 .. 215360)  W1f  [g=31][ht=3][lane=64][e=8] W1 A-frags (NEW)

#define NS 65536
#define K2LOG2E 2.885390082f
#define KLOG2E 1.4426950408889634f
#define KLN2 0.6931471805599453f

typedef __attribute__((ext_vector_type(8))) short short8;
typedef __attribute__((ext_vector_type(4))) float f32x4;

__device__ inline unsigned short f2bf(float f) {
  unsigned int u = __builtin_bit_cast(unsigned int, f);
  u += 0x7fffu + ((u >> 16) & 1u);          // RNE
  return (unsigned short)(u >> 16);
}
__device__ inline unsigned int cvt_pk_bf16(float lo, float hi) {
  unsigned int r;
  asm("v_cvt_pk_bf16_f32 %0, %1, %2" : "=v"(r) : "v"(lo), "v"(hi));
  return r;
}
__device__ inline float bf2f(unsigned short s) {
  return __builtin_bit_cast(float, (unsigned int)s << 16);
}
// input pre-scaled by 2log2e: tanh = 1 - 2/(1+exp2(z))
__device__ inline float tanh_pre(float z) {
  float t = __builtin_amdgcn_exp2f(z);
  float r = __builtin_amdgcn_rcpf(t + 1.0f);
  return fmaf(-2.0f, r, 1.0f);
}
__device__ inline short8 ld8bf(const float* p) {
  f32x4 a = *reinterpret_cast<const f32x4*>(p);
  f32x4 b = *reinterpret_cast<const f32x4*>(p + 4);
  union { short8 s; unsigned int u[4]; } t;
  t.u[0] = cvt_pk_bf16(a[0], a[1]);
  t.u[1] = cvt_pk_bf16(a[2], a[3]);
  t.u[2] = cvt_pk_bf16(b[0], b[1]);
  t.u[3] = cvt_pk_bf16(b[2], b[3]);
  return t.s;
}

__global__ void maf_prep(const float* __restrict__ W1, const float* __restrict__ Wc,
                         const float* __restrict__ W2, const float* __restrict__ b1,
                         unsigned short* __restrict__ ws) {
  int t = blockIdx.x * blockDim.x + threadIdx.x;
  if (t < 32768) {                                   // W1mT [h][d], masked+scaled
    int h = t >> 5, d = t & 31;
    int deg = h % 31 + 1;
    float v = (deg >= d + 1) ? W1[(size_t)d * 1024 + h] * K2LOG2E : 0.f;
    ws[t] = f2bf(v);
  } else if (t < 98304) {                            // WcT [h][c], scaled
    int i = t - 32768;
    int h = i >> 6, c = i & 63;
    ws[t] = f2bf(Wc[(size_t)c * 1024 + h] * K2LOG2E);
  } else if (t < 161792) {                           // W2f: chunk0 B-frags (q-perm)
    int i = t - 98304;
    int g = i / 2048, r = i % 2048;
    int ct = r >> 9, q = r & 511;
    int lane = q >> 3, e = q & 7;
    int l15 = lane & 15, lk = lane >> 4;
    int c = 16 * ct + l15;
    int kw = 8 * lk + e;                             // 0..31 (chunk0)
    int lkk = kw >> 3, jp = (kw >> 2) & 1, rr = kw & 3;
    int slot = jp * 16 + 4 * lkk + rr;               // q-perm slot (<32)
    int cnt = (g == 0) ? 34 : 33;
    int h = g + 31 * slot, d = c >> 1;
    float v = (slot < cnt && d > g) ? W2[(size_t)h * 64 + c] : 0.f;
    if (c & 1) v *= KLOG2E;
    ws[t] = f2bf(v);
  } else if (t < 165760) {                           // W2t: slots 32/33 tail
    int i = t - 161792;
    int g = i >> 7, r = i & 127;
    int c = r >> 1, which = r & 1;
    int slot = 32 + which;
    int cnt = (g == 0) ? 34 : 33;
    int h = g + 31 * slot, d = c >> 1;
    float v = (slot < cnt && d > g) ? W2[(size_t)h * 64 + c] : 0.f;
    if (c & 1) v *= KLOG2E;
    ws[t] = f2bf(v);
  } else if (t < 167744) {                           // b1g [g][slot]
    int i = t - 165760;
    int g = i >> 6, sl = i & 63;
    int cnt = (g == 0) ? 34 : 33;
    float v = (sl < cnt) ? b1[g + 31 * sl] * K2LOG2E : 0.f;
    ws[t] = f2bf(v);
  } else if (t < 215360) {                           // W1f: coalesced W1 A-frags (NEW)
    int i = t - 167744;
    int g = i / 1536, r = i % 1536;
    int ht = r >> 9, q = r & 511;
    int lane = q >> 3, e = q & 7;
    int l15 = lane & 15, lk = lane >> 4;
    int j = 16 * ht + l15, d = 8 * lk + e;
    int cnt = (g == 0) ? 34 : 33;
    int h = g + 31 * j;
    float v = (j < cnt && d <= g) ? W1[(size_t)d * 1024 + h] * K2LOG2E : 0.f;
    ws[t] = f2bf(v);
  }
}

__global__ __launch_bounds__(256, 1) void maf_main(
    const float* __restrict__ x, const float* __restrict__ ctx,
    const float* __restrict__ b2, const unsigned short* __restrict__ ws,
    float* __restrict__ out)
{
  // LDS: 20480 + 33280 = 53760 B. All wave-private; zero barriers.
  __shared__ __align__(16) unsigned short ybf[256][40];   // y bf16 [s][d]
  __shared__ __align__(16) float xT[32][260];             // x transposed [d][s]

  const unsigned short* WcT  = ws + 32768;     // [1024][64]
  const unsigned short* W2f  = ws + 98304;     // [31][4][512]
  const unsigned short* W2t  = ws + 161792;    // [31][128]
  const unsigned short* b1g  = ws + 165760;    // [31][64]
  const unsigned short* W1f  = ws + 167744;    // [31][3][512]

  const int tid  = threadIdx.x;
  const int lane = tid & 63;
  const int w    = tid >> 6;        // wave 0..3: owns samples [64w, 64w+64)
  const int l15  = lane & 15;
  const int lk   = lane >> 4;
  const int s0   = blockIdx.x * 256;
  const int sw   = 64 * w;

  // ---- zero own ybf rows (64 rows x 40 u16 = 1280 u32) ----
  {
    unsigned int* p = reinterpret_cast<unsigned int*>(&ybf[sw][0]);
    for (int i = lane; i < 1280; i += 64) p[i] = 0u;
  }
  // ---- xT staging: thread stages its own sample (tid) -> wave-private cols ----
  {
    const float* xp = x + (size_t)(s0 + tid) * 32;
#pragma unroll
    for (int q = 0; q < 8; ++q) {
      f32x4 v = *reinterpret_cast<const f32x4*>(xp + 4 * q);
#pragma unroll
      for (int i = 0; i < 4; ++i) xT[4 * q + i][tid] = v[i];
    }
  }
  // ---- ctx -> registers (4 tiles x 2 frags) ----
  short8 cB[4][2];
#pragma unroll
  for (int st = 0; st < 4; ++st) {
    const float* c0 = ctx + (size_t)(s0 + sw + 16 * st + l15) * 64;
    cB[st][0] = ld8bf(c0 + 8 * lk);
    cB[st][1] = ld8bf(c0 + 32 + 8 * lk);
  }

  // ---- P accumulators acc[st][ct] (b2 folded; ls cols log2-scaled) ----
  f32x4 acc[4][4];
  {
    float bs = (l15 & 1) ? KLOG2E : 1.0f;
#pragma unroll
    for (int ct = 0; ct < 4; ++ct) {
      float v = b2[16 * ct + l15] * bs;
      f32x4 bv = {v, v, v, v};
#pragma unroll
      for (int st = 0; st < 4; ++st) acc[st][ct] = bv;
    }
  }
  f32x4 ls[4];
#pragma unroll
  for (int st = 0; st < 4; ++st) ls[st] = (f32x4){0.f, 0.f, 0.f, 0.f};

#define LOADW(P, G) {                                                             \
    const int gg_ = (G);                                                          \
    const int cnt_ = (gg_ == 0) ? 34 : 33;                                        \
    _Pragma("unroll")                                                             \
    for (int ht = 0; ht < 3; ++ht) {                                              \
      P##_w1[ht] = *reinterpret_cast<const short8*>(W1f + (size_t)(gg_ * 3 + ht) * 512 + lane * 8); \
      int j_ = 16 * ht + l15;                                                     \
      bool vld_ = j_ < cnt_;                                                      \
      int h_ = vld_ ? (gg_ + 31 * j_) : 0;                                        \
      short8 a2_ = *reinterpret_cast<const short8*>(WcT + (size_t)h_ * 64 + 8 * lk);  \
      short8 a3_ = *reinterpret_cast<const short8*>(WcT + (size_t)h_ * 64 + 32 + 8 * lk); \
      short8 z_ = {0, 0, 0, 0, 0, 0, 0, 0};                                       \
      if (!vld_) { a2_ = z_; a3_ = z_; }                                          \
      P##_c0[ht] = a2_; P##_c1[ht] = a3_;                                         \
    } }

#define LOADW2(P, G) {                                                            \
    const int gg_ = (G);                                                          \
    _Pragma("unroll")                                                             \
    for (int ct = 0; ct < 4; ++ct) {                                              \
      P##_w2[ct] = *reinterpret_cast<const short8*>(W2f + (size_t)(gg_ * 4 + ct) * 512 + lane * 8); \
      unsigned int tv = *reinterpret_cast<const unsigned int*>(W2t + (size_t)gg_ * 128 + 2 * (16 * ct + l15)); \
      P##_t2[ct] = (lk == 0) ? tv : 0u;                                           \
    } }

#define LOADB(P, G) {                                                             \
    const int gg_ = (G);                                                          \
    _Pragma("unroll")                                                             \
    for (int ht = 0; ht < 3; ++ht) {                                              \
      const unsigned short* bp_ = b1g + 64 * gg_ + 16 * ht + 4 * lk;              \
      P##_b1[ht] = (f32x4){bf2f(bp_[0]), bf2f(bp_[1]), bf2f(bp_[2]), bf2f(bp_[3])}; \
    } }

#define COMPUTE(P, G) {                                                           \
    _Pragma("unroll")                                                             \
    for (int st = 0; st < 4; ++st) {                                              \
      short8 yB_ = *reinterpret_cast<const short8*>(&ybf[sw + 16 * st + l15][8 * lk]); \
      unsigned int pa[3][2];                                                      \
      _Pragma("unroll")                                                           \
      for (int ht = 0; ht < 3; ++ht) {                                            \
        f32x4 C = P##_b1[ht];                                                     \
        C = __builtin_amdgcn_mfma_f32_16x16x32_bf16(P##_w1[ht], yB_, C, 0, 0, 0); \
        C = __builtin_amdgcn_mfma_f32_16x16x32_bf16(P##_c0[ht], cB[st][0], C, 0, 0, 0); \
        C = __builtin_amdgcn_mfma_f32_16x16x32_bf16(P##_c1[ht], cB[st][1], C, 0, 0, 0); \
        pa[ht][0] = cvt_pk_bf16(tanh_pre(C[0]), tanh_pre(C[1]));                  \
        pa[ht][1] = cvt_pk_bf16(tanh_pre(C[2]), tanh_pre(C[3]));                  \
      }                                                                           \
      union { unsigned int u[4]; short8 s; } A0_, A1_, B1_;                       \
      A0_.u[0] = pa[0][0]; A0_.u[1] = pa[0][1];                                   \
      A0_.u[2] = pa[1][0]; A0_.u[3] = pa[1][1];                                   \
      A1_.u[0] = pa[2][0]; A1_.u[1] = pa[2][1]; A1_.u[2] = 0; A1_.u[3] = 0;       \
      _Pragma("unroll")                                                           \
      for (int ct = 0; ct < 4; ++ct) {                                            \
        B1_.u[0] = P##_t2[ct]; B1_.u[1] = 0; B1_.u[2] = 0; B1_.u[3] = 0;          \
        acc[st][ct] = __builtin_amdgcn_mfma_f32_16x16x32_bf16(A0_.s, P##_w2[ct], acc[st][ct], 0, 0, 0); \
        acc[st][ct] = __builtin_amdgcn_mfma_f32_16x16x32_bf16(A1_.s, B1_.s, acc[st][ct], 0, 0, 0); \
      }                                                                           \
    } }

#define EMIT(T) {                                                                 \
    const int t_ = (T);                                                           \
    const int cte_ = t_ >> 3;                                                     \
    const int li_ = 2 * (t_ & 7);                                                 \
    _Pragma("unroll")                                                             \
    for (int st = 0; st < 4; ++st) {                                              \
      f32x4 av = cte_ == 0 ? acc[st][0] : cte_ == 1 ? acc[st][1]                  \
               : cte_ == 2 ? acc[st][2] : acc[st][3];                             \
      f32x4 pv;                                                                   \
      _Pragma("unroll")                                                           \
      for (int r = 0; r < 4; ++r) pv[r] = __shfl_xor(av[r], 1);                   \
      if (l15 == li_) {                                                           \
        f32x4 x4 = *reinterpret_cast<const f32x4*>(&xT[t_][sw + 16 * st + 4 * lk]); \
        _Pragma("unroll")                                                         \
        for (int r = 0; r < 4; ++r) {                                             \
          float y0 = fmaf(x4[r], __builtin_amdgcn_exp2f(pv[r]), av[r]);           \
          ybf[sw + 16 * st + 4 * lk + r][t_] = f2bf(y0);                          \
          out[(size_t)(s0 + sw + 16 * st + 4 * lk + r) * 32 + t_] = y0;           \
        }                                                                         \
        ls[st] += pv;                                                             \
      }                                                                           \
    } }

  // ---- ping-pong weight sets ----
  short8 WA_w1[3], WA_c0[3], WA_c1[3], WA_w2[4];
  short8 WB_w1[3], WB_c0[3], WB_c1[3], WB_w2[4];
  unsigned int WA_t2[4], WB_t2[4];
  f32x4 WA_b1[3], WB_b1[3];
  LOADW(WA, 0) LOADW2(WA, 0) LOADB(WA, 0)

#pragma unroll 1
  for (int t = 0; t < 30; t += 2) {
    EMIT(t)
    LOADW(WB, t + 1) LOADW2(WB, t + 1) LOADB(WB, t + 1)
    COMPUTE(WA, t)
    EMIT(t + 1)
    LOADW(WA, t + 2) LOADW2(WA, t + 2) LOADB(WA, t + 2)
    COMPUTE(WB, t + 1)
  }
  EMIT(30)
  COMPUTE(WA, 30)
  EMIT(31)

  // ---- log_det: reduce over even-l15 lanes (bits 1..3), per tile ----
#pragma unroll
  for (int st = 0; st < 4; ++st) {
    f32x4 v = ls[st];
#pragma unroll
    for (int off = 2; off <= 8; off <<= 1)
#pragma unroll
      for (int r = 0; r < 4; ++r) v[r] += __shfl_xor(v[r], off);
    if (l15 == 0) {
#pragma unroll
      for (int r = 0; r < 4; ++r)
        out[(size_t)NS * 32 + s0 + sw + 16 * st + 4 * lk + r] = v[r] * KLN2;
    }
  }
}

extern "C" void kernel_launch(void* const* d_in, const int* in_sizes, int n_in,
                              void* d_out, int out_size, void* d_ws, size_t ws_size,
                              hipStream_t stream) {
  (void)in_sizes; (void)n_in; (void)out_size; (void)ws_size;
  const float* x   = (const float*)d_in[0];
  const float* ctx = (const float*)d_in[1];
  const float* W1  = (const float*)d_in[2];
  const float* b1  = (const float*)d_in[3];
  const float* Wc  = (const float*)d_in[4];
  const float* W2  = (const float*)d_in[5];
  const float* b2  = (const float*)d_in[6];
  unsigned short* ws = (unsigned short*)d_ws;
  float* out = (float*)d_out;

  maf_prep<<<842, 256, 0, stream>>>(W1, Wc, W2, b1, ws);
  maf_main<<<256, 256, 0, stream>>>(x, ctx, b2, ws, out);
}

// Round 24
// 77.475 us; speedup vs baseline: 2.8760x; 1.2104x over previous
//
#include <hip/hip_runtime.h>

// MAF forward, single-pass autoregressive. N=65536, D=32, H=1024, C=64.
// R23 = R22's weight layout/prep BYTE-IDENTICAL (W2f/W2t/W1f coalesced; WcT/b1g
//   demand; bug X isolated to the untried Wcf swizzle, left alone) with the TLP
//   knob re-tested post-swizzle: 32 samples/wave (2 tiles), 512 blocks x 256 thr
//   -> 2048 waves = 2/SIMD (R22: 64 spw -> 1024 waves = 1/SIMD, 60% idle from
//   an unhidden per-step latency chain). R17's TLP regression was confounded by
//   pre-swizzle gather doubling; W1/W2 streams are now coalesced.
// ws layout (u16):
//   [0      ..  32768)  W1mT [h=1024][d=32] (dead, kept: no relocation)
//   [32768  ..  98304)  WcT  [h=1024][c=64] = Wc[c][h] * 2log2e
//   [98304  .. 161792)  W2f  [g=31][ct=4][lane=64][e=8] chunk0 B-frags (q-perm)
//   [161792 .. 165760)  W2t  [g=31][c=64][which=2] slots 32/33 tail
//   [165760 .. 167744)  b1g  [g=31][slot=64] = b1*2log2e (0 pads)
//   [167744 .. 215360)  W1f  [g=31][ht=3][lane=64][e=8] W1 A-frags

#define NS 65536
#define K2LOG2E 2.885390082f
#define KLOG2E 1.4426950408889634f
#define KLN2 0.6931471805599453f

typedef __attribute__((ext_vector_type(8))) short short8;
typedef __attribute__((ext_vector_type(4))) float f32x4;

__device__ inline unsigned short f2bf(float f) {
  unsigned int u = __builtin_bit_cast(unsigned int, f);
  u += 0x7fffu + ((u >> 16) & 1u);          // RNE
  return (unsigned short)(u >> 16);
}
__device__ inline unsigned int cvt_pk_bf16(float lo, float hi) {
  unsigned int r;
  asm("v_cvt_pk_bf16_f32 %0, %1, %2" : "=v"(r) : "v"(lo), "v"(hi));
  return r;
}
__device__ inline float bf2f(unsigned short s) {
  return __builtin_bit_cast(float, (unsigned int)s << 16);
}
// input pre-scaled by 2log2e: tanh = 1 - 2/(1+exp2(z))
__device__ inline float tanh_pre(float z) {
  float t = __builtin_amdgcn_exp2f(z);
  float r = __builtin_amdgcn_rcpf(t + 1.0f);
  return fmaf(-2.0f, r, 1.0f);
}
__device__ inline short8 ld8bf(const float* p) {
  f32x4 a = *reinterpret_cast<const f32x4*>(p);
  f32x4 b = *reinterpret_cast<const f32x4*>(p + 4);
  union { short8 s; unsigned int u[4]; } t;
  t.u[0] = cvt_pk_bf16(a[0], a[1]);
  t.u[1] = cvt_pk_bf16(a[2], a[3]);
  t.u[2] = cvt_pk_bf16(b[0], b[1]);
  t.u[3] = cvt_pk_bf16(b[2], b[3]);
  return t.s;
}

__global__ void maf_prep(const float* __restrict__ W1, const float* __restrict__ Wc,
                         const float* __restrict__ W2, const float* __restrict__ b1,
                         unsigned short* __restrict__ ws) {
  int t = blockIdx.x * blockDim.x + threadIdx.x;
  if (t < 32768) {                                   // W1mT (dead region, kept)
    int h = t >> 5, d = t & 31;
    int deg = h % 31 + 1;
    float v = (deg >= d + 1) ? W1[(size_t)d * 1024 + h] * K2LOG2E : 0.f;
    ws[t] = f2bf(v);
  } else if (t < 98304) {                            // WcT [h][c], scaled
    int i = t - 32768;
    int h = i >> 6, c = i & 63;
    ws[t] = f2bf(Wc[(size_t)c * 1024 + h] * K2LOG2E);
  } else if (t < 161792) {                           // W2f: chunk0 B-frags (q-perm)
    int i = t - 98304;
    int g = i / 2048, r = i % 2048;
    int ct = r >> 9, q = r & 511;
    int lane = q >> 3, e = q & 7;
    int l15 = lane & 15, lk = lane >> 4;
    int c = 16 * ct + l15;
    int kw = 8 * lk + e;                             // 0..31 (chunk0)
    int lkk = kw >> 3, jp = (kw >> 2) & 1, rr = kw & 3;
    int slot = jp * 16 + 4 * lkk + rr;               // q-perm slot (<32)
    int cnt = (g == 0) ? 34 : 33;
    int h = g + 31 * slot, d = c >> 1;
    float v = (slot < cnt && d > g) ? W2[(size_t)h * 64 + c] : 0.f;
    if (c & 1) v *= KLOG2E;
    ws[t] = f2bf(v);
  } else if (t < 165760) {                           // W2t: slots 32/33 tail
    int i = t - 161792;
    int g = i >> 7, r = i & 127;
    int c = r >> 1, which = r & 1;
    int slot = 32 + which;
    int cnt = (g == 0) ? 34 : 33;
    int h = g + 31 * slot, d = c >> 1;
    float v = (slot < cnt && d > g) ? W2[(size_t)h * 64 + c] : 0.f;
    if (c & 1) v *= KLOG2E;
    ws[t] = f2bf(v);
  } else if (t < 167744) {                           // b1g [g][slot]
    int i = t - 165760;
    int g = i >> 6, sl = i & 63;
    int cnt = (g == 0) ? 34 : 33;
    float v = (sl < cnt) ? b1[g + 31 * sl] * K2LOG2E : 0.f;
    ws[t] = f2bf(v);
  } else if (t < 215360) {                           // W1f: coalesced W1 A-frags
    int i = t - 167744;
    int g = i / 1536, r = i % 1536;
    int ht = r >> 9, q = r & 511;
    int lane = q >> 3, e = q & 7;
    int l15 = lane & 15, lk = lane >> 4;
    int j = 16 * ht + l15, d = 8 * lk + e;
    int cnt = (g == 0) ? 34 : 33;
    int h = g + 31 * j;
    float v = (j < cnt && d <= g) ? W1[(size_t)d * 1024 + h] * K2LOG2E : 0.f;
    ws[t] = f2bf(v);
  }
}

__global__ __launch_bounds__(256, 2) void maf_main(
    const float* __restrict__ x, const float* __restrict__ ctx,
    const float* __restrict__ b2, const unsigned short* __restrict__ ws,
    float* __restrict__ out)
{
  // LDS: 10240 + 16896 = 27136 B (2 blocks/CU fine). All wave-private; 0 barriers.
  __shared__ __align__(16) unsigned short ybf[128][40];   // y bf16 [s][d]
  __shared__ __align__(16) float xT[32][132];             // x transposed [d][s]

  const unsigned short* WcT  = ws + 32768;     // [1024][64]
  const unsigned short* W2f  = ws + 98304;     // [31][4][512]
  const unsigned short* W2t  = ws + 161792;    // [31][128]
  const unsigned short* b1g  = ws + 165760;    // [31][64]
  const unsigned short* W1f  = ws + 167744;    // [31][3][512]

  const int tid  = threadIdx.x;
  const int lane = tid & 63;
  const int w    = tid >> 6;        // wave 0..3: owns samples [32w, 32w+32)
  const int l15  = lane & 15;
  const int lk   = lane >> 4;
  const int s0   = blockIdx.x * 128;
  const int sw   = 32 * w;

  // ---- zero own ybf rows (32 rows x 40 u16 = 640 u32) ----
  {
    unsigned int* p = reinterpret_cast<unsigned int*>(&ybf[sw][0]);
    for (int i = lane; i < 640; i += 64) p[i] = 0u;
  }
  // ---- xT staging (wave-private: thread stages sample tid>>1) ----
  {
    int s = tid >> 1, q = tid & 1;
    const float* xp = x + (size_t)(s0 + s) * 32 + 16 * q;
#pragma unroll
    for (int c4 = 0; c4 < 4; ++c4) {
      f32x4 v = *reinterpret_cast<const f32x4*>(xp + 4 * c4);
#pragma unroll
      for (int i = 0; i < 4; ++i) xT[16 * q + 4 * c4 + i][s] = v[i];
    }
  }
  // ---- ctx -> registers (2 tiles x 2 frags) ----
  short8 cB[2][2];
#pragma unroll
  for (int st = 0; st < 2; ++st) {
    const float* c0 = ctx + (size_t)(s0 + sw + 16 * st + l15) * 64;
    cB[st][0] = ld8bf(c0 + 8 * lk);
    cB[st][1] = ld8bf(c0 + 32 + 8 * lk);
  }

  // ---- P accumulators acc[st][ct] (b2 folded; ls cols log2-scaled) ----
  f32x4 acc[2][4];
  {
    float bs = (l15 & 1) ? KLOG2E : 1.0f;
#pragma unroll
    for (int ct = 0; ct < 4; ++ct) {
      float v = b2[16 * ct + l15] * bs;
      f32x4 bv = {v, v, v, v};
#pragma unroll
      for (int st = 0; st < 2; ++st) acc[st][ct] = bv;
    }
  }
  f32x4 ls[2];
#pragma unroll
  for (int st = 0; st < 2; ++st) ls[st] = (f32x4){0.f, 0.f, 0.f, 0.f};

#define LOADW(P, G) {                                                             \
    const int gg_ = (G);                                                          \
    const int cnt_ = (gg_ == 0) ? 34 : 33;                                        \
    _Pragma("unroll")                                                             \
    for (int ht = 0; ht < 3; ++ht) {                                              \
      P##_w1[ht] = *reinterpret_cast<const short8*>(W1f + (size_t)(gg_ * 3 + ht) * 512 + lane * 8); \
      int j_ = 16 * ht + l15;                                                     \
      bool vld_ = j_ < cnt_;                                                      \
      int h_ = vld_ ? (gg_ + 31 * j_) : 0;                                        \
      short8 a2_ = *reinterpret_cast<const short8*>(WcT + (size_t)h_ * 64 + 8 * lk);  \
      short8 a3_ = *reinterpret_cast<const short8*>(WcT + (size_t)h_ * 64 + 32 + 8 * lk); \
      short8 z_ = {0, 0, 0, 0, 0, 0, 0, 0};                                       \
      if (!vld_) { a2_ = z_; a3_ = z_; }                                          \
      P##_c0[ht] = a2_; P##_c1[ht] = a3_;                                         \
    } }

#define LOADW2(P, G) {                                                            \
    const int gg_ = (G);                                                          \
    _Pragma("unroll")                                                             \
    for (int ct = 0; ct < 4; ++ct) {                                              \
      P##_w2[ct] = *reinterpret_cast<const short8*>(W2f + (size_t)(gg_ * 4 + ct) * 512 + lane * 8); \
      unsigned int tv = *reinterpret_cast<const unsigned int*>(W2t + (size_t)gg_ * 128 + 2 * (16 * ct + l15)); \
      P##_t2[ct] = (lk == 0) ? tv : 0u;                                           \
    } }

#define LOADB(P, G) {                                                             \
    const int gg_ = (G);                                                          \
    _Pragma("unroll")                                                             \
    for (int ht = 0; ht < 3; ++ht) {                                              \
      const unsigned short* bp_ = b1g + 64 * gg_ + 16 * ht + 4 * lk;              \
      P##_b1[ht] = (f32x4){bf2f(bp_[0]), bf2f(bp_[1]), bf2f(bp_[2]), bf2f(bp_[3])}; \
    } }

#define COMPUTE(P, G) {                                                           \
    _Pragma("unroll")                                                             \
    for (int st = 0; st < 2; ++st) {                                              \
      short8 yB_ = *reinterpret_cast<const short8*>(&ybf[sw + 16 * st + l15][8 * lk]); \
      unsigned int pa[3][2];                                                      \
      _Pragma("unroll")                                                           \
      for (int ht = 0; ht < 3; ++ht) {                                            \
        f32x4 C = P##_b1[ht];                                                     \
        C = __builtin_amdgcn_mfma_f32_16x16x32_bf16(P##_w1[ht], yB_, C, 0, 0, 0); \
        C = __builtin_amdgcn_mfma_f32_16x16x32_bf16(P##_c0[ht], cB[st][0], C, 0, 0, 0); \
        C = __builtin_amdgcn_mfma_f32_16x16x32_bf16(P##_c1[ht], cB[st][1], C, 0, 0, 0); \
        pa[ht][0] = cvt_pk_bf16(tanh_pre(C[0]), tanh_pre(C[1]));                  \
        pa[ht][1] = cvt_pk_bf16(tanh_pre(C[2]), tanh_pre(C[3]));                  \
      }                                                                           \
      union { unsigned int u[4]; short8 s; } A0_, A1_, B1_;                       \
      A0_.u[0] = pa[0][0]; A0_.u[1] = pa[0][1];                                   \
      A0_.u[2] = pa[1][0]; A0_.u[3] = pa[1][1];                                   \
      A1_.u[0] = pa[2][0]; A1_.u[1] = pa[2][1]; A1_.u[2] = 0; A1_.u[3] = 0;       \
      _Pragma("unroll")                                                           \
      for (int ct = 0; ct < 4; ++ct) {                                            \
        B1_.u[0] = P##_t2[ct]; B1_.u[1] = 0; B1_.u[2] = 0; B1_.u[3] = 0;          \
        acc[st][ct] = __builtin_amdgcn_mfma_f32_16x16x32_bf16(A0_.s, P##_w2[ct], acc[st][ct], 0, 0, 0); \
        acc[st][ct] = __builtin_amdgcn_mfma_f32_16x16x32_bf16(A1_.s, B1_.s, acc[st][ct], 0, 0, 0); \
      }                                                                           \
    } }

#define EMIT(T) {                                                                 \
    const int t_ = (T);                                                           \
    const int cte_ = t_ >> 3;                                                     \
    const int li_ = 2 * (t_ & 7);                                                 \
    _Pragma("unroll")                                                             \
    for (int st = 0; st < 2; ++st) {                                              \
      f32x4 av = cte_ == 0 ? acc[st][0] : cte_ == 1 ? acc[st][1]                  \
               : cte_ == 2 ? acc[st][2] : acc[st][3];                             \
      f32x4 pv;                                                                   \
      _Pragma("unroll")                                                           \
      for (int r = 0; r < 4; ++r) pv[r] = __shfl_xor(av[r], 1);                   \
      if (l15 == li_) {                                                           \
        f32x4 x4 = *reinterpret_cast<const f32x4*>(&xT[t_][sw + 16 * st + 4 * lk]); \
        _Pragma("unroll")                                                         \
        for (int r = 0; r < 4; ++r) {                                             \
          float y0 = fmaf(x4[r], __builtin_amdgcn_exp2f(pv[r]), av[r]);           \
          ybf[sw + 16 * st + 4 * lk + r][t_] = f2bf(y0);                          \
          out[(size_t)(s0 + sw + 16 * st + 4 * lk + r) * 32 + t_] = y0;           \
        }                                                                         \
        ls[st] += pv;                                                             \
      }                                                                           \
    } }

  // ---- ping-pong weight sets ----
  short8 WA_w1[3], WA_c0[3], WA_c1[3], WA_w2[4];
  short8 WB_w1[3], WB_c0[3], WB_c1[3], WB_w2[4];
  unsigned int WA_t2[4], WB_t2[4];
  f32x4 WA_b1[3], WB_b1[3];
  LOADW(WA, 0) LOADW2(WA, 0) LOADB(WA, 0)

#pragma unroll 1
  for (int t = 0; t < 30; t += 2) {
    EMIT(t)
    LOADW(WB, t + 1) LOADW2(WB, t + 1) LOADB(WB, t + 1)
    COMPUTE(WA, t)
    EMIT(t + 1)
    LOADW(WA, t + 2) LOADW2(WA, t + 2) LOADB(WA, t + 2)
    COMPUTE(WB, t + 1)
  }
  EMIT(30)
  COMPUTE(WA, 30)
  EMIT(31)

  // ---- log_det: reduce over even-l15 lanes (bits 1..3), per tile ----
#pragma unroll
  for (int st = 0; st < 2; ++st) {
    f32x4 v = ls[st];
#pragma unroll
    for (int off = 2; off <= 8; off <<= 1)
#pragma unroll
      for (int r = 0; r < 4; ++r) v[r] += __shfl_xor(v[r], off);
    if (l15 == 0) {
#pragma unroll
      for (int r = 0; r < 4; ++r)
        out[(size_t)NS * 32 + s0 + sw + 16 * st + 4 * lk + r] = v[r] * KLN2;
    }
  }
}

extern "C" void kernel_launch(void* const* d_in, const int* in_sizes, int n_in,
                              void* d_out, int out_size, void* d_ws, size_t ws_size,
                              hipStream_t stream) {
  (void)in_sizes; (void)n_in; (void)out_size; (void)ws_size;
  const float* x   = (const float*)d_in[0];
  const float* ctx = (const float*)d_in[1];
  const float* W1  = (const float*)d_in[2];
  const float* b1  = (const float*)d_in[3];
  const float* Wc  = (const float*)d_in[4];
  const float* W2  = (const float*)d_in[5];
  const float* b2  = (const float*)d_in[6];
  unsigned short* ws = (unsigned short*)d_ws;
  float* out = (float*)d_out;

  maf_prep<<<842, 256, 0, stream>>>(W1, Wc, W2, b1, ws);
  maf_main<<<512, 256, 0, stream>>>(x, ctx, b2, ws, out);
}